// Round 2
// 303.986 us; speedup vs baseline: 1.0013x; 1.0013x over previous
//
#include <hip/hip_runtime.h>

#define D 4096
#define RANK 8
#define BLOCK 1024
#define GRID 256
#define NW (BLOCK / 64)  // 16 waves

typedef float f4 __attribute__((ext_vector_type(4)));

// Raw workgroup barrier with LDS-only ordering. __syncthreads() would emit
// s_waitcnt vmcnt(0) before s_barrier (workgroup fence semantics), draining
// the prefetch loads and the previous pair's global stores every iteration.
// We only ever need LDS (s_c / s_w) visibility across the barrier, so wait
// on lgkmcnt alone and let global ops stay in flight across it.
__device__ __forceinline__ void lds_barrier() {
  asm volatile("s_waitcnt lgkmcnt(0)" ::: "memory");
  __builtin_amdgcn_s_barrier();
  asm volatile("" ::: "memory");
}

// ---------------------------------------------------------------------------
// Compact-WY: H7..H0 = I - V T V^T (V = normalized cols of hra_u).
// One persistent block per CU (1024 thr). Each thread owns 4 contiguous
// d-elements (one float4) and keeps its normalized V slice (4x8 = 32 regs)
// in registers for the whole kernel.
// Row loop processes PAIRS of rows, software-pipelined with ONE barrier/iter:
//   iter p: dots(pair p) -> lane0 writes s_c[p&1]
//           wave0 worker: w = T c for pair p-1 (concurrent with other waves)
//           lds_barrier()   <-- raw s_barrier, lgkmcnt-only drain
//           all: read s_w[(p-1)&1], update + store pair p-1
// ---------------------------------------------------------------------------
__global__ __launch_bounds__(BLOCK, 4) void hra_fused(
    const float* __restrict__ x_in, const float* __restrict__ u_raw,
    float* __restrict__ y, int rows) {
  __shared__ float s_g[NW][36];
  __shared__ float s_G[36];
  __shared__ float s_Gn[64];
  __shared__ float s_T[64];
  __shared__ float s_invn[8];
  __shared__ float s_c[2][2][NW][8];  // [buf][row][wave][coef]
  __shared__ float s_w[2][2][8];      // [buf][row][coef]

  const int t = threadIdx.x;
  const int lane = t & 63;
  const int wid = t >> 6;

  // ---- load raw u slice: 4 contiguous d-elements, 8 coeffs each ----
  float v[4][8];
#pragma unroll
  for (int q = 0; q < 4; ++q) {
    const int d = 4 * t + q;
    const f4* p = (const f4*)(u_raw + (size_t)d * RANK);
    f4 a0 = p[0];
    f4 a1 = p[1];
    v[q][0] = a0.x; v[q][1] = a0.y; v[q][2] = a0.z; v[q][3] = a0.w;
    v[q][4] = a1.x; v[q][5] = a1.y; v[q][6] = a1.z; v[q][7] = a1.w;
  }

  // ---- Gram partials (packed upper triangle, 36 values) ----
  {
    float g[36];
#pragma unroll
    for (int k = 0; k < 36; ++k) g[k] = 0.f;
#pragma unroll
    for (int q = 0; q < 4; ++q) {
      int idx = 0;
#pragma unroll
      for (int i = 0; i < 8; ++i)
#pragma unroll
        for (int j = i; j < 8; ++j)
          g[idx++] += v[q][i] * v[q][j];
    }
#pragma unroll
    for (int off = 32; off >= 1; off >>= 1) {
#pragma unroll
      for (int k = 0; k < 36; ++k)
        g[k] += __shfl_xor(g[k], off, 64);
    }
    if (lane == 0) {
#pragma unroll
      for (int k = 0; k < 36; ++k) s_g[wid][k] = g[k];
    }
  }
  __syncthreads();

  if (t < 36) {
    float s = 0.f;
#pragma unroll
    for (int w2 = 0; w2 < NW; ++w2) s += s_g[w2][t];
    s_G[t] = s;
  }
  __syncthreads();

  if (t < 8) {
    const int dix[8] = {0, 8, 15, 21, 26, 30, 33, 35};
    s_invn[t] = rsqrtf(s_G[dix[t]]);
  }
  __syncthreads();

  if (t < 64) {
    const int i = t >> 3, j = t & 7;
    const int ii = i < j ? i : j;
    const int jj = i < j ? j : i;
    const int idx = ii * 8 - (ii * (ii - 1)) / 2 + (jj - ii);
    s_Gn[t] = s_G[idx] * s_invn[i] * s_invn[j];
  }
  __syncthreads();

  if (t < 8) {
    // column-parallel WY recurrence
    const int j = t;
    for (int k = 0; k < j; ++k) s_T[k * 8 + j] = 0.f;
    s_T[j * 8 + j] = 2.f;
    for (int k = j + 1; k < 8; ++k) {
      float s = 0.f;
      for (int l = j; l < k; ++l) s += s_Gn[k * 8 + l] * s_T[l * 8 + j];
      s_T[k * 8 + j] = -2.f * s;
    }
  }
  __syncthreads();

  // normalize V; load worker's T row (row index (t>>2)&7 — the worker mapping)
  {
    float invn[8];
#pragma unroll
    for (int i = 0; i < 8; ++i) invn[i] = s_invn[i];
#pragma unroll
    for (int q = 0; q < 4; ++q)
#pragma unroll
      for (int i = 0; i < 8; ++i) v[q][i] *= invn[i];
  }
  float Trow[8];
#pragma unroll
  for (int k = 0; k < 8; ++k) Trow[k] = s_T[((t >> 2) & 7) * 8 + k];

  // ---- pipelined pair loop ----
  const int rpb = rows / GRID;  // 32
  const int npair = rpb / 2;    // 16
  const int base = blockIdx.x * rpb;

  f4 nxt0 = *(const f4*)(x_in + (size_t)(base + 0) * D + 4 * t);
  f4 nxt1 = *(const f4*)(x_in + (size_t)(base + 1) * D + 4 * t);
  f4 cur0, cur1, prv0, prv1;

#pragma unroll 2
  for (int p = 0; p < npair; ++p) {
    cur0 = nxt0;
    cur1 = nxt1;
    const float xc0[4] = {cur0.x, cur0.y, cur0.z, cur0.w};
    const float xc1[4] = {cur1.x, cur1.y, cur1.z, cur1.w};

    // dots for pair p
    float acc[2][8];
#pragma unroll
    for (int i = 0; i < 8; ++i) { acc[0][i] = 0.f; acc[1][i] = 0.f; }
#pragma unroll
    for (int q = 0; q < 4; ++q)
#pragma unroll
      for (int i = 0; i < 8; ++i) {
        acc[0][i] += xc0[q] * v[q][i];
        acc[1][i] += xc1[q] * v[q][i];
      }

    // prefetch pair p+1 (clamped)
    const int pn = (p + 1 < npair) ? p + 1 : p;
    nxt0 = *(const f4*)(x_in + (size_t)(base + 2 * pn) * D + 4 * t);
    nxt1 = *(const f4*)(x_in + (size_t)(base + 2 * pn + 1) * D + 4 * t);

    // butterfly (both rows)
#pragma unroll
    for (int off = 32; off >= 1; off >>= 1) {
#pragma unroll
      for (int i = 0; i < 8; ++i) {
        acc[0][i] += __shfl_xor(acc[0][i], off, 64);
        acc[1][i] += __shfl_xor(acc[1][i], off, 64);
      }
    }
    if (lane == 0) {
      f4 a0 = {acc[0][0], acc[0][1], acc[0][2], acc[0][3]};
      f4 a1 = {acc[0][4], acc[0][5], acc[0][6], acc[0][7]};
      f4 b0 = {acc[1][0], acc[1][1], acc[1][2], acc[1][3]};
      f4 b1 = {acc[1][4], acc[1][5], acc[1][6], acc[1][7]};
      *(f4*)&s_c[p & 1][0][wid][0] = a0;
      *(f4*)&s_c[p & 1][0][wid][4] = a1;
      *(f4*)&s_c[p & 1][1][wid][0] = b0;
      *(f4*)&s_c[p & 1][1][wid][4] = b1;
    }

    // worker phase (wave 0 only): w = T c for pair p-1
    if (p > 0 && t < 64) {
      const int row = t >> 5;       // 0..1
      const int j = (t >> 2) & 7;   // coef (matches Trow)
      const int s = t & 3;          // wave-slice
      const float* cb = &s_c[(p - 1) & 1][row][0][0];
      f4 cl = *(const f4*)(cb + s * 8) + *(const f4*)(cb + (s + 4) * 8) +
              *(const f4*)(cb + (s + 8) * 8) + *(const f4*)(cb + (s + 12) * 8);
      f4 ch = *(const f4*)(cb + s * 8 + 4) + *(const f4*)(cb + (s + 4) * 8 + 4) +
              *(const f4*)(cb + (s + 8) * 8 + 4) + *(const f4*)(cb + (s + 12) * 8 + 4);
      float wsum = Trow[0] * cl.x + Trow[1] * cl.y + Trow[2] * cl.z +
                   Trow[3] * cl.w + Trow[4] * ch.x + Trow[5] * ch.y +
                   Trow[6] * ch.z + Trow[7] * ch.w;
      wsum += __shfl_xor(wsum, 1, 64);
      wsum += __shfl_xor(wsum, 2, 64);
      if (s == 0) s_w[(p - 1) & 1][row][j] = wsum;
      (void)j;
    }

    lds_barrier();  // the ONLY barrier per iteration — LDS-ordering only,
                    // global loads/stores remain in flight across it

    // update + store pair p-1
    if (p > 0) {
      float w0[8], w1[8];
#pragma unroll
      for (int i = 0; i < 8; ++i) {
        w0[i] = s_w[(p - 1) & 1][0][i];
        w1[i] = s_w[(p - 1) & 1][1][i];
      }
      float xp0[4] = {prv0.x, prv0.y, prv0.z, prv0.w};
      float xp1[4] = {prv1.x, prv1.y, prv1.z, prv1.w};
#pragma unroll
      for (int q = 0; q < 4; ++q) {
        float s0 = 0.f, s1 = 0.f;
#pragma unroll
        for (int i = 0; i < 8; ++i) {
          s0 += w0[i] * v[q][i];
          s1 += w1[i] * v[q][i];
        }
        xp0[q] -= s0;
        xp1[q] -= s1;
      }
      f4 o0 = {xp0[0], xp0[1], xp0[2], xp0[3]};
      f4 o1 = {xp1[0], xp1[1], xp1[2], xp1[3]};
      *(f4*)(y + (size_t)(base + 2 * (p - 1)) * D + 4 * t) = o0;
      *(f4*)(y + (size_t)(base + 2 * (p - 1) + 1) * D + 4 * t) = o1;
    }
    prv0 = cur0;
    prv1 = cur1;
  }

  // ---- epilogue: worker + update for the last pair ----
  {
    const int pl = npair - 1;
    if (t < 64) {
      const int row = t >> 5;
      const int j = (t >> 2) & 7;
      const int s = t & 3;
      const float* cb = &s_c[pl & 1][row][0][0];
      f4 cl = *(const f4*)(cb + s * 8) + *(const f4*)(cb + (s + 4) * 8) +
              *(const f4*)(cb + (s + 8) * 8) + *(const f4*)(cb + (s + 12) * 8);
      f4 ch = *(const f4*)(cb + s * 8 + 4) + *(const f4*)(cb + (s + 4) * 8 + 4) +
              *(const f4*)(cb + (s + 8) * 8 + 4) + *(const f4*)(cb + (s + 12) * 8 + 4);
      float wsum = Trow[0] * cl.x + Trow[1] * cl.y + Trow[2] * cl.z +
                   Trow[3] * cl.w + Trow[4] * ch.x + Trow[5] * ch.y +
                   Trow[6] * ch.z + Trow[7] * ch.w;
      wsum += __shfl_xor(wsum, 1, 64);
      wsum += __shfl_xor(wsum, 2, 64);
      if (s == 0) s_w[pl & 1][row][j] = wsum;
    }
    lds_barrier();

    float w0[8], w1[8];
#pragma unroll
    for (int i = 0; i < 8; ++i) {
      w0[i] = s_w[pl & 1][0][i];
      w1[i] = s_w[pl & 1][1][i];
    }
    float xp0[4] = {prv0.x, prv0.y, prv0.z, prv0.w};
    float xp1[4] = {prv1.x, prv1.y, prv1.z, prv1.w};
#pragma unroll
    for (int q = 0; q < 4; ++q) {
      float s0 = 0.f, s1 = 0.f;
#pragma unroll
      for (int i = 0; i < 8; ++i) {
        s0 += w0[i] * v[q][i];
        s1 += w1[i] * v[q][i];
      }
      xp0[q] -= s0;
      xp1[q] -= s1;
    }
    f4 o0 = {xp0[0], xp0[1], xp0[2], xp0[3]};
    f4 o1 = {xp1[0], xp1[1], xp1[2], xp1[3]};
    *(f4*)(y + (size_t)(base + 2 * pl) * D + 4 * t) = o0;
    *(f4*)(y + (size_t)(base + 2 * pl + 1) * D + 4 * t) = o1;
  }
}

extern "C" void kernel_launch(void* const* d_in, const int* in_sizes, int n_in,
                              void* d_out, int out_size, void* d_ws, size_t ws_size,
                              hipStream_t stream) {
  const float* x_in = (const float*)d_in[0];
  const float* u = (const float*)d_in[1];
  float* y = (float*)d_out;
  (void)d_ws; (void)ws_size;

  const int rows = in_sizes[0] / D;  // 8192

  hipLaunchKernelGGL(hra_fused, dim3(GRID), dim3(BLOCK), 0, stream,
                     x_in, u, y, rows);
}